// Round 12
// baseline (438.170 us; speedup 1.0000x reference)
//
#include <hip/hip_runtime.h>

#define NF 64
#define NH 32
#define NK 16
#define NNODES 15
#define BLOCK 512
#define NWAVES (BLOCK / 64)
#define SPB 1008              // real samples per block (512 A + 496 B)
#define PSLOTS (1024 + 16)    // padded slot capacity (holes <= 8)

// r12 = r11 resubmitted after an infra container failure (audit found no
// deadlock/OOB; hardened the two formally-out-of-range __shfl indices).
//
// Design: r10 (2 samples/lane, shared weight stream) + PAIR-ALIGNED bucket
// padding -> locA==locB for EVERY pair by construction -> dual path deleted.
//   r10 evidence: 2 samples/lane cut dur 373->315 (LDS-pipe model holds),
//   but the wave-granular __all gate left ~{8,7,5,1}/8 waves shared per
//   level -> level 3 nearly all-dual (2x LDS reads + 2x serialized bodies).
//   Fix: pad each bucket base to even in the scan; odd buckets get one
//   sentinel hole (valid=0, loc=b). Capacity: 1008 real + <=8 holes <=
//   1024 slots. Invalids excluded from ballots; tail slots pre-filled with
//   loc-0 sentinels. Within-wave multi-node W2 reads are 2-4-way LDS
//   aliases (free/cheap per m136).
// Register rules (r1-r3): no runtime-indexed reg arrays; rolled g indexes
// memory only; k loops fully unrolled. Occupancy lesson (r8/r9): attr min
// sets allocator budget only; (2,4) = 256-VGPR budget, no spill.
// Per-sample FP order identical to r5/r10 (absmax must stay 0).
// Spill guard: WRITE_SIZE must stay ~3 MB.

__global__ __attribute__((amdgpu_flat_work_group_size(BLOCK, BLOCK),
                          amdgpu_waves_per_eu(2, 4)))
void tree_mlp_kernel(
    const float* __restrict__ x,
    const float* __restrict__ W1, const float* __restrict__ b1,
    const float* __restrict__ W2, const float* __restrict__ b2,
    const float* __restrict__ W3, const float* __restrict__ b3,
    const float* __restrict__ leaf_best, const int* __restrict__ subset_idx,
    float* __restrict__ out, int N)
{
    __shared__ __align__(16) float W2Lv[8 * 1024];   // 32 KB: this level's nodes
    __shared__ int      subL[NNODES * NK];           // 960 B
    __shared__ __align__(8) unsigned permL[PSLOTS];  // 4160 B
    __shared__ int      sortL[64];                   // nb*NWAVES <= 64
    __shared__ int      padL[8];                     // per-bucket pad offset

    const int tid  = threadIdx.x;
    const int lane = tid & 63;
    const int wv   = tid >> 6;
    const unsigned long long lt =
        (lane == 0) ? 0ull : ((~0ull) >> (64 - lane));

    for (int i = tid; i < NNODES * NK; i += BLOCK) subL[i] = subset_idx[i];
    {
        const float4* src = (const float4*)W2;       // node 0
        float4* dst = (float4*)W2Lv;
        for (int i = tid; i < 256; i += BLOCK) dst[i] = src[i];
    }
    __syncthreads();

    const int base = blockIdx.x * SPB;
    int idA = base + tid;                  // samples 0..511
    int idB = base + BLOCK + tid;          // samples 512..1007 (tid < 496)
    int vA = (idA < N) ? 1 : 0;                      if (!vA) idA = 0;
    int vB = (tid < SPB - BLOCK && idB < N) ? 1 : 0; if (!vB) idB = 0;
    int locA = 0, locB = 0, off = 0;

    #pragma unroll 1   // keep level loop rolled (I$)
    for (int level = 0; level < 4; ++level) {
        if (level > 0) {
            // ---- counting sort by loc with pair-aligned bucket bases ----
            const int nb = 1 << level;
            // Pre-fill tail slots with loc-0 sentinels (valid=0).
            *(unsigned long long*)(permL + 2 * tid) = 0ull;
            int rkA = 0, rkB = 0;
            #pragma unroll 1
            for (int b = 0; b < nb; ++b) {
                const unsigned long long mA = __ballot(vA && locA == b);
                const unsigned long long mB = __ballot(vB && locB == b);
                if (vA && locA == b) rkA = __popcll(mA & lt);
                if (vB && locB == b) rkB = __popcll(mA) + __popcll(mB & lt);
                if (lane == 0)
                    sortL[b * NWAVES + wv] = __popcll(mA) + __popcll(mB);
            }
            __syncthreads();   // counts + sentinels visible; W2Lv reads done

            // Stage this level's W2 slice (overlaps wave-0's scan).
            {
                const int cnt4 = (1 << level) * 256;            // float4s
                const float4* src = (const float4*)(W2 + (size_t)off * 1024);
                float4* dst = (float4*)W2Lv;
                for (int i = tid; i < cnt4; i += BLOCK) dst[i] = src[i];
            }
            // Wave-parallel exclusive scan + per-bucket even-padding.
            if (wv == 0) {
                const int cnt = nb * NWAVES;                    // 16/32/64
                int v = (lane < cnt) ? sortL[lane] : 0;
                int incl = v;
                #pragma unroll
                for (int d = 1; d < 64; d <<= 1) {
                    int t = __shfl_up(incl, d, 64);
                    if (lane >= d) incl += t;
                }
                if (lane < cnt) sortL[lane] = incl - v;         // exclusive
                // lane b < nb: bucket total T[b], pad = #odd buckets before b.
                // shfl source indices clamped to [0,63] (values consumed only
                // for lane < nb <= 8; clamp avoids formal out-of-range UB).
                const int iCb = (lane < 8) ? (NWAVES * lane + NWAVES - 1) : 63;
                const int iCm = (lane >= 1 && lane < 8) ? (NWAVES * lane - 1) : 0;
                const int Cb    = __shfl(incl, iCb, 64);
                const int Cm    = __shfl(incl, iCm, 64);
                const int Cprev = (lane == 0) ? 0 : Cm;
                const int Tb    = Cb - Cprev;
                const int odd   = Tb & 1;
                int po = odd;
                #pragma unroll
                for (int d = 1; d < 8; d <<= 1) {
                    int t = __shfl_up(po, d, 64);
                    if (lane >= d) po += t;
                }
                if (lane < nb) {
                    const int padb = po - odd;
                    padL[lane] = padb;
                    if (odd)   // hole sentinel: valid=0, loc=b, id=0
                        permL[Cprev + padb + Tb] = (unsigned)lane;
                }
            }
            __syncthreads();

            if (vA) permL[sortL[locA * NWAVES + wv] + padL[locA] + rkA]
                  = ((unsigned)idA << 5) | (1u << 4) | (unsigned)locA;
            if (vB) permL[sortL[locB * NWAVES + wv] + padL[locB] + rkB]
                  = ((unsigned)idB << 5) | (1u << 4) | (unsigned)locB;
            __syncthreads();
            const unsigned pA = permL[2 * tid];
            const unsigned pB = permL[2 * tid + 1];
            idA = (int)(pA >> 5); vA = (int)((pA >> 4) & 1u); locA = (int)(pA & 15u);
            idB = (int)(pB >> 5); vB = (int)((pB >> 4) & 1u); locB = (int)(pB & 15u);
            __syncthreads();           // protect permL/sortL reuse next level
        }

        // locB == locA for every pair by construction.
        const int node = off + locA;
        int bitA, bitB;
        {
            const int* si = subL + node * NK;
            const float* xrA = x + (size_t)idA * NF;
            const float* xrB = x + (size_t)idB * NF;
            float xsA[NK], xsB[NK];
            #pragma unroll
            for (int k = 0; k < NK; ++k) {
                const int f = si[k];
                xsA[k] = xrA[f];
                xsB[k] = xrB[f];
            }

            float h1A[NH], h1B[NH];
            {
                const float4* w1g = (const float4*)(W1 + node * (NH * NK));
                const float*  b1g = b1 + node * NH;
                #pragma unroll
                for (int j = 0; j < NH; ++j) {
                    const float bj = b1g[j];
                    float aA = bj, aB = bj;
                    #pragma unroll
                    for (int q = 0; q < NK / 4; ++q) {
                        const float4 t = w1g[j * 4 + q];
                        aA += t.x * xsA[q * 4 + 0]; aB += t.x * xsB[q * 4 + 0];
                        aA += t.y * xsA[q * 4 + 1]; aB += t.y * xsB[q * 4 + 1];
                        aA += t.z * xsA[q * 4 + 2]; aB += t.z * xsB[q * 4 + 2];
                        aA += t.w * xsA[q * 4 + 3]; aB += t.w * xsB[q * 4 + 3];
                    }
                    h1A[j] = (aA >= 0.f) ? aA : 0.01f * aA;
                    h1B[j] = (aB >= 0.f) ? aB : 0.01f * aB;
                }
            }

            const float* w2l = W2Lv + (locA << 10);
            const float* bb2 = b2 + node * NH;
            const float* w3g = W3 + node * 2 * NH;
            const float bi0 = b3[node * 2 + 0];
            const float bi1 = b3[node * 2 + 1];
            float l0A = bi0, l1A = bi1, l0B = bi0, l1B = bi1;

            #pragma unroll 2
            for (int g = 0; g < NH; ++g) {
                const float bg = bb2[g];
                float aA = bg, aB = bg;
                const float4* row = (const float4*)(w2l + g * NH);
                #pragma unroll
                for (int q = 0; q < NH / 4; ++q) {
                    const float4 t = row[q];
                    aA += t.x * h1A[q * 4 + 0]; aB += t.x * h1B[q * 4 + 0];
                    aA += t.y * h1A[q * 4 + 1]; aB += t.y * h1B[q * 4 + 1];
                    aA += t.z * h1A[q * 4 + 2]; aB += t.z * h1B[q * 4 + 2];
                    aA += t.w * h1A[q * 4 + 3]; aB += t.w * h1B[q * 4 + 3];
                }
                const float h2A = (aA >= 0.f) ? aA : 0.01f * aA;
                const float h2B = (aB >= 0.f) ? aB : 0.01f * aB;
                const float wa = w3g[g];
                const float wb = w3g[NH + g];
                l0A += wa * h2A; l1A += wb * h2A;
                l0B += wa * h2B; l1B += wb * h2B;
            }
            bitA = (l0A < l1A) ? 1 : 0;
            bitB = (l0B < l1B) ? 1 : 0;
        }

        locA = 2 * locA + bitA;
        locB = 2 * locB + bitB;
        off = 2 * off + 1;   // node offsets: 0, 1, 3, 7
    }

    if (vA) out[idA] = leaf_best[locA];
    if (vB) out[idB] = leaf_best[locB];
}

extern "C" void kernel_launch(void* const* d_in, const int* in_sizes, int n_in,
                              void* d_out, int out_size, void* d_ws, size_t ws_size,
                              hipStream_t stream) {
    const float* x         = (const float*)d_in[0];
    const float* W1        = (const float*)d_in[1];
    const float* b1        = (const float*)d_in[2];
    const float* W2        = (const float*)d_in[3];
    const float* b2        = (const float*)d_in[4];
    const float* W3        = (const float*)d_in[5];
    const float* b3        = (const float*)d_in[6];
    const float* leaf_best = (const float*)d_in[7];
    const int*   subset    = (const int*)d_in[8];

    const int N = in_sizes[0] / NF;
    const int grid = (N + SPB - 1) / SPB;
    tree_mlp_kernel<<<grid, BLOCK, 0, stream>>>(
        x, W1, b1, W2, b2, W3, b3, leaf_best, subset, (float*)d_out, N);
}